// Round 4
// baseline (634.770 us; speedup 1.0000x reference)
//
#include <hip/hip_runtime.h>
#include <hip/hip_bf16.h>
#include <stdint.h>

typedef _Float16 f16;
typedef __attribute__((ext_vector_type(8))) _Float16 f16x8;
typedef __attribute__((ext_vector_type(4))) _Float16 f16x4;
typedef __attribute__((ext_vector_type(4))) float f32x4;

#define GLOBAL_AS __attribute__((address_space(1)))
#define LDS_AS __attribute__((address_space(3)))

#define D_DIM 768
#define NTOK 1024
#define NSLOT 16
#define NB 32
#define NTOT (NB*NTOK)   // 32768
#define HDIM 512
#define INNER 3072
#define SLOTSZ (512*768)
#define SCALE_D 0.03608439182435161f   // 768^-0.5
#define SCALE_H 0.125f                 // 64^-0.5

// ---------- MFMA GEMM 64x64, BK=128 (4 panels), split-K ----------
// OUT: 1 = f16 store, 3 = f32 store into buffer z (multi-buffer split-K).
template<int OUT>
__global__ __launch_bounds__(256) void mgemm64_k(
    const f16* __restrict__ A, const f16* __restrict__ Bt,
    void* __restrict__ Cout, int M, int N, int K, int Kc)
{
  __shared__ __align__(16) f16 As[64*128];
  __shared__ __align__(16) f16 Bs[64*128];
  const int tid = threadIdx.x;
  const int lane = tid & 63;
  const int wave = tid >> 6;
  const int m0 = blockIdx.x*64, n0 = blockIdx.y*64;
  const int kbeg = blockIdx.z * Kc;
  const int wm = (wave>>1)*32, wn = (wave&1)*32;
  const int quad = lane>>4, l16 = lane&15;

  const int sr = tid>>2;
  const int sc = (tid&3)*8;
  const f16* gA = A  + (size_t)(m0+sr)*K + kbeg + sc;
  const f16* gB = Bt + (size_t)(n0+sr)*K + kbeg + sc;
  LDS_AS f16* lA = (LDS_AS f16*)&As[(size_t)tid*8];
  LDS_AS f16* lB = (LDS_AS f16*)&Bs[(size_t)tid*8];

  const f16* fA0 = &As[(wm + l16)*32 + quad*8];
  const f16* fB0 = &Bs[(wn + l16)*32 + quad*8];

  f32x4 acc[2][2] = {};

  for (int k0 = 0; k0 < Kc; k0 += 128){
    #pragma unroll
    for (int p=0;p<4;++p){
      __builtin_amdgcn_global_load_lds((const GLOBAL_AS void*)(gA + k0 + p*32),
                                       (LDS_AS void*)(lA + (size_t)p*2048), 16, 0, 0);
      __builtin_amdgcn_global_load_lds((const GLOBAL_AS void*)(gB + k0 + p*32),
                                       (LDS_AS void*)(lB + (size_t)p*2048), 16, 0, 0);
    }
    __syncthreads();
    #pragma unroll
    for (int p=0;p<4;++p){
      f16x8 a0 = *(const f16x8*)(fA0 + p*2048);
      f16x8 a1 = *(const f16x8*)(fA0 + p*2048 + 16*32);
      f16x8 b0 = *(const f16x8*)(fB0 + p*2048);
      f16x8 b1 = *(const f16x8*)(fB0 + p*2048 + 16*32);
      acc[0][0] = __builtin_amdgcn_mfma_f32_16x16x32_f16(a0,b0,acc[0][0],0,0,0);
      acc[0][1] = __builtin_amdgcn_mfma_f32_16x16x32_f16(a0,b1,acc[0][1],0,0,0);
      acc[1][0] = __builtin_amdgcn_mfma_f32_16x16x32_f16(a1,b0,acc[1][0],0,0,0);
      acc[1][1] = __builtin_amdgcn_mfma_f32_16x16x32_f16(a1,b1,acc[1][1],0,0,0);
    }
    __syncthreads();
  }
  const size_t zoff = (size_t)blockIdx.z * M * N;
  #pragma unroll
  for (int mt=0;mt<2;++mt){
    #pragma unroll
    for (int nt=0;nt<2;++nt){
      int gm = m0 + wm + mt*16 + quad*4;
      int gn = n0 + wn + nt*16 + l16;
      #pragma unroll
      for (int r=0;r<4;++r){
        float c = acc[mt][nt][r];
        size_t idx = (size_t)(gm+r)*N + gn;
        if (OUT==1) ((f16*)Cout)[idx] = (f16)c;
        else        ((float*)Cout)[zoff + idx] = c;
      }
    }
  }
}

// ---------- W1 + GLU fused ----------
__global__ __launch_bounds__(256) void w1glu_k(
    const f16* __restrict__ A, const f16* __restrict__ W1T,
    f16* __restrict__ act, int M)
{
  __shared__ __align__(16) f16 As[64*128];
  __shared__ __align__(16) f16 Bu[64*128];
  __shared__ __align__(16) f16 Bg[64*128];
  const int K = 768;
  const int tid = threadIdx.x;
  const int lane = tid & 63;
  const int wave = tid >> 6;
  const int m0 = blockIdx.x*64, n0 = blockIdx.y*64;
  const int wm = (wave>>1)*32, wn = (wave&1)*32;
  const int quad = lane>>4, l16 = lane&15;

  const int sr = tid>>2;
  const int sc = (tid&3)*8;
  const f16* gA  = A   + (size_t)(m0+sr)*K + sc;
  const f16* gBu = W1T + (size_t)(n0+sr)*K + sc;
  const f16* gBg = W1T + (size_t)(3072+n0+sr)*K + sc;
  LDS_AS f16* lA  = (LDS_AS f16*)&As[(size_t)tid*8];
  LDS_AS f16* lBu = (LDS_AS f16*)&Bu[(size_t)tid*8];
  LDS_AS f16* lBg = (LDS_AS f16*)&Bg[(size_t)tid*8];

  const f16* fA0 = &As[(wm + l16)*32 + quad*8];
  const f16* fU0 = &Bu[(wn + l16)*32 + quad*8];
  const f16* fG0 = &Bg[(wn + l16)*32 + quad*8];

  f32x4 accU[2][2] = {};
  f32x4 accG[2][2] = {};

  for (int k0 = 0; k0 < K; k0 += 128){
    #pragma unroll
    for (int p=0;p<4;++p){
      __builtin_amdgcn_global_load_lds((const GLOBAL_AS void*)(gA  + k0 + p*32),
                                       (LDS_AS void*)(lA  + (size_t)p*2048), 16, 0, 0);
      __builtin_amdgcn_global_load_lds((const GLOBAL_AS void*)(gBu + k0 + p*32),
                                       (LDS_AS void*)(lBu + (size_t)p*2048), 16, 0, 0);
      __builtin_amdgcn_global_load_lds((const GLOBAL_AS void*)(gBg + k0 + p*32),
                                       (LDS_AS void*)(lBg + (size_t)p*2048), 16, 0, 0);
    }
    __syncthreads();
    #pragma unroll
    for (int p=0;p<4;++p){
      f16x8 a0 = *(const f16x8*)(fA0 + p*2048);
      f16x8 a1 = *(const f16x8*)(fA0 + p*2048 + 16*32);
      f16x8 u0 = *(const f16x8*)(fU0 + p*2048);
      f16x8 u1 = *(const f16x8*)(fU0 + p*2048 + 16*32);
      f16x8 g0 = *(const f16x8*)(fG0 + p*2048);
      f16x8 g1 = *(const f16x8*)(fG0 + p*2048 + 16*32);
      accU[0][0] = __builtin_amdgcn_mfma_f32_16x16x32_f16(a0,u0,accU[0][0],0,0,0);
      accU[0][1] = __builtin_amdgcn_mfma_f32_16x16x32_f16(a0,u1,accU[0][1],0,0,0);
      accU[1][0] = __builtin_amdgcn_mfma_f32_16x16x32_f16(a1,u0,accU[1][0],0,0,0);
      accU[1][1] = __builtin_amdgcn_mfma_f32_16x16x32_f16(a1,u1,accU[1][1],0,0,0);
      accG[0][0] = __builtin_amdgcn_mfma_f32_16x16x32_f16(a0,g0,accG[0][0],0,0,0);
      accG[0][1] = __builtin_amdgcn_mfma_f32_16x16x32_f16(a0,g1,accG[0][1],0,0,0);
      accG[1][0] = __builtin_amdgcn_mfma_f32_16x16x32_f16(a1,g0,accG[1][0],0,0,0);
      accG[1][1] = __builtin_amdgcn_mfma_f32_16x16x32_f16(a1,g1,accG[1][1],0,0,0);
    }
    __syncthreads();
  }
  #pragma unroll
  for (int mt=0;mt<2;++mt){
    #pragma unroll
    for (int nt=0;nt<2;++nt){
      int gm = m0 + wm + mt*16 + quad*4;
      int gn = n0 + wn + nt*16 + l16;
      #pragma unroll
      for (int r=0;r<4;++r){
        float u = accU[mt][nt][r];
        float g = accG[mt][nt][r];
        float sg = g / (1.0f + __expf(-g));
        act[(size_t)(gm+r)*INNER + gn] = (f16)(u*sg);
      }
    }
  }
}

// ---------- MFMA dots (q_eff @ xn^T) + inverted softmax + EPS + partial rowsum ----------
// q_eff comes as 3 f32 split-K partials, summed during staging.
__global__ __launch_bounds__(256) void dots_k(
    const float* __restrict__ Q0, const float* __restrict__ Q1,
    const float* __restrict__ Q2,
    const f16* __restrict__ Xn,   // [32768,768]
    f16* __restrict__ attn,       // [32,16,1024] f16
    float* __restrict__ rsPart)   // [32][16 jt][16 i]
{
  __shared__ __align__(16) f16 qf[16*768];    // A-frag layout, 24 KB
  __shared__ __align__(16) f16 ks[64*128];    // 4 panels [64][32], 16 KB
  __shared__ float rpart[4][16];
  const int b = blockIdx.x, jt = blockIdx.y;
  const int tid = threadIdx.x;
  const int lane = tid & 63;
  const int w = tid >> 6;
  const int quad = lane>>4, l16 = lane&15;

  #pragma unroll
  for (int c=0;c<6;++c){
    int p = c*256 + tid;
    int ki = p >> 6, qd = (p >> 4) & 3, rw = p & 15;
    size_t qo = ((size_t)(b*NSLOT+rw))*D_DIM + ki*32 + qd*8;
    float4 a0 = *(const float4*)(Q0+qo), a1 = *(const float4*)(Q0+qo+4);
    float4 b0 = *(const float4*)(Q1+qo), b1 = *(const float4*)(Q1+qo+4);
    float4 c0 = *(const float4*)(Q2+qo), c1 = *(const float4*)(Q2+qo+4);
    f16x8 v;
    v[0]=(f16)(a0.x+b0.x+c0.x); v[1]=(f16)(a0.y+b0.y+c0.y);
    v[2]=(f16)(a0.z+b0.z+c0.z); v[3]=(f16)(a0.w+b0.w+c0.w);
    v[4]=(f16)(a1.x+b1.x+c1.x); v[5]=(f16)(a1.y+b1.y+c1.y);
    v[6]=(f16)(a1.z+b1.z+c1.z); v[7]=(f16)(a1.w+b1.w+c1.w);
    *(f16x8*)&qf[(size_t)p*8] = v;
  }

  const f16* gK = Xn + ((size_t)(b*NTOK + jt*64 + (tid>>2)))*D_DIM + (tid&3)*8;
  LDS_AS f16* lK = (LDS_AS f16*)&ks[(size_t)tid*8];

  f32x4 acc = {};
  for (int it=0; it<6; ++it){
    #pragma unroll
    for (int p=0;p<4;++p)
      __builtin_amdgcn_global_load_lds((const GLOBAL_AS void*)(gK + it*128 + p*32),
                                       (LDS_AS void*)(lK + (size_t)p*2048), 16, 0, 0);
    __syncthreads();
    #pragma unroll
    for (int p=0;p<4;++p){
      f16x8 a  = *(const f16x8*)&qf[(((size_t)(it*4+p)*4 + quad)*16 + l16)*8];
      f16x8 bf = *(const f16x8*)&ks[(size_t)p*2048 + (w*16+l16)*32 + quad*8];
      acc = __builtin_amdgcn_mfma_f32_16x16x32_f16(a, bf, acc, 0, 0, 0);
    }
    __syncthreads();
  }

  float v0 = acc[0]*SCALE_D, v1 = acc[1]*SCALE_D, v2 = acc[2]*SCALE_D, v3 = acc[3]*SCALE_D;
  float mx = fmaxf(fmaxf(v0,v1), fmaxf(v2,v3));
  mx = fmaxf(mx, __shfl_xor(mx, 16));
  mx = fmaxf(mx, __shfl_xor(mx, 32));
  float e0 = __expf(v0-mx), e1 = __expf(v1-mx), e2 = __expf(v2-mx), e3 = __expf(v3-mx);
  float s = e0+e1+e2+e3;
  s += __shfl_xor(s, 16);
  s += __shfl_xor(s, 32);
  float inv = 1.0f/s;
  float a0 = e0*inv + 1e-8f, a1 = e1*inv + 1e-8f, a2 = e2*inv + 1e-8f, a3 = e3*inv + 1e-8f;

  int jcol = jt*64 + w*16 + l16;
  int ibase = b*NSLOT + quad*4;
  attn[(size_t)(ibase+0)*NTOK + jcol] = (f16)a0;
  attn[(size_t)(ibase+1)*NTOK + jcol] = (f16)a1;
  attn[(size_t)(ibase+2)*NTOK + jcol] = (f16)a2;
  attn[(size_t)(ibase+3)*NTOK + jcol] = (f16)a3;

  float t0=a0, t1=a1, t2=a2, t3=a3;
  #pragma unroll
  for (int m=1;m<16;m<<=1){
    t0 += __shfl_xor(t0, m);
    t1 += __shfl_xor(t1, m);
    t2 += __shfl_xor(t2, m);
    t3 += __shfl_xor(t3, m);
  }
  if (l16 == 0){
    rpart[w][quad*4+0] = t0;
    rpart[w][quad*4+1] = t1;
    rpart[w][quad*4+2] = t2;
    rpart[w][quad*4+3] = t3;
  }
  __syncthreads();
  if (tid < 16){
    float ss = rpart[0][tid] + rpart[1][tid] + rpart[2][tid] + rpart[3][tid];
    rsPart[(size_t)((b*16 + jt)<<4) + tid] = ss;
  }
}

// ---------- t = (attn @ xn) / rowsum via MFMA on xnT; t -> f16 ----------
__global__ __launch_bounds__(256) void attnv_k(
    const f16* __restrict__ attn,   // [32,16,1024] f16
    const float* __restrict__ rsPart,
    const f16* __restrict__ XnT,    // [768, 32768]
    f16* __restrict__ t_out)        // [32,16,768] f16
{
  __shared__ __align__(16) f16 Asl[16*128];
  __shared__ __align__(16) f16 Bsl[64*128];
  __shared__ float rsum[16];
  const int b = blockIdx.x, d0 = blockIdx.y*64;
  const int tid = threadIdx.x;
  const int lane = tid & 63;
  const int w = tid >> 6;
  const int quad = lane>>4, l16 = lane&15;

  if (tid < 16){
    float s = 0.f;
    #pragma unroll
    for (int jt=0;jt<16;++jt) s += rsPart[(size_t)((b*16 + jt)<<4) + tid];
    rsum[tid] = s;
  }

  const int pa = tid>>6, ta = tid&63;
  const f16* gA = attn + ((size_t)(b*NSLOT + (ta>>2)))*NTOK + pa*32 + (ta&3)*8;
  LDS_AS f16* lA = (LDS_AS f16*)&Asl[(size_t)pa*512 + ta*8];
  const f16* gB = XnT + ((size_t)(d0 + (tid>>2)))*NTOT + b*NTOK + (tid&3)*8;
  LDS_AS f16* lB = (LDS_AS f16*)&Bsl[(size_t)tid*8];

  f32x4 acc = {};
  for (int it=0; it<8; ++it){
    __builtin_amdgcn_global_load_lds((const GLOBAL_AS void*)(gA + it*128),
                                     (LDS_AS void*)lA, 16, 0, 0);
    #pragma unroll
    for (int p=0;p<4;++p)
      __builtin_amdgcn_global_load_lds((const GLOBAL_AS void*)(gB + it*128 + p*32),
                                       (LDS_AS void*)(lB + (size_t)p*2048), 16, 0, 0);
    __syncthreads();
    #pragma unroll
    for (int p=0;p<4;++p){
      f16x8 a  = *(const f16x8*)&Asl[(size_t)p*512 + l16*32 + quad*8];
      f16x8 bf = *(const f16x8*)&Bsl[(size_t)p*2048 + (w*16+l16)*32 + quad*8];
      acc = __builtin_amdgcn_mfma_f32_16x16x32_f16(a, bf, acc, 0, 0, 0);
    }
    __syncthreads();
  }
  int dcol = d0 + w*16 + l16;
  #pragma unroll
  for (int r=0;r<4;++r){
    int i = quad*4 + r;
    t_out[(size_t)(b*NSLOT + i)*D_DIM + dcol] = (f16)(acc[r] / rsum[i]);
  }
}

// ---------- wave-per-row LN (4 rows/block), f16 out ----------
__global__ __launch_bounds__(256) void lnw_k(
    const float* __restrict__ X,
    const float* __restrict__ g, const float* __restrict__ bb,
    f16* __restrict__ out)
{
  const int lane = threadIdx.x & 63;
  const size_t row = (size_t)blockIdx.x*4 + (threadIdx.x>>6);
  const float* x = X + row*D_DIM;
  float4 v[3]; float s=0.f, ss=0.f;
  #pragma unroll
  for (int t=0;t<3;++t){
    v[t] = *(const float4*)(x + lane*4 + t*256);
    s  += v[t].x+v[t].y+v[t].z+v[t].w;
    ss += v[t].x*v[t].x+v[t].y*v[t].y+v[t].z*v[t].z+v[t].w*v[t].w;
  }
  #pragma unroll
  for (int m=1;m<64;m<<=1){ s += __shfl_xor(s,m); ss += __shfl_xor(ss,m); }
  float mean = s*(1.0f/768.0f);
  float inv  = rsqrtf(ss*(1.0f/768.0f) - mean*mean + 1e-5f);
  #pragma unroll
  for (int t=0;t<3;++t){
    int c0 = lane*4 + t*256;
    float4 gg = *(const float4*)(g + c0);
    float4 bv = *(const float4*)(bb + c0);
    f16x4 h4;
    h4.x = (f16)((v[t].x-mean)*inv*gg.x + bv.x);
    h4.y = (f16)((v[t].y-mean)*inv*gg.y + bv.y);
    h4.z = (f16)((v[t].z-mean)*inv*gg.z + bv.z);
    h4.w = (f16)((v[t].w-mean)*inv*gg.w + bv.w);
    *(f16x4*)(out + row*D_DIM + c0) = h4;
  }
}

// ---------- residual + 3-way-split sum, double LN: out1=LN(S+U0+U1+U2,g1,b1) f32, out2=LN(out1,g2,b2) f16 ----------
__global__ __launch_bounds__(256) void lnln_res_k(
    const float* __restrict__ S,  const float* __restrict__ U0,
    const float* __restrict__ U1, const float* __restrict__ U2,
    const float* __restrict__ g1, const float* __restrict__ b1,
    const float* __restrict__ g2, const float* __restrict__ b2,
    float* __restrict__ out1, f16* __restrict__ out2)
{
  const int lane = threadIdx.x & 63;
  const size_t row = (size_t)blockIdx.x*4 + (threadIdx.x>>6);
  const size_t ro = row*D_DIM;
  float4 v[3]; float s=0.f, ss=0.f;
  #pragma unroll
  for (int t=0;t<3;++t){
    int c0 = lane*4 + t*256;
    float4 a = *(const float4*)(S + ro + c0);
    float4 b = *(const float4*)(U0 + ro + c0);
    float4 c = *(const float4*)(U1 + ro + c0);
    float4 d = *(const float4*)(U2 + ro + c0);
    v[t].x = a.x+b.x+c.x+d.x; v[t].y = a.y+b.y+c.y+d.y;
    v[t].z = a.z+b.z+c.z+d.z; v[t].w = a.w+b.w+c.w+d.w;
    s  += v[t].x+v[t].y+v[t].z+v[t].w;
    ss += v[t].x*v[t].x+v[t].y*v[t].y+v[t].z*v[t].z+v[t].w*v[t].w;
  }
  #pragma unroll
  for (int m=1;m<64;m<<=1){ s += __shfl_xor(s,m); ss += __shfl_xor(ss,m); }
  float mean = s*(1.0f/768.0f);
  float inv  = rsqrtf(ss*(1.0f/768.0f) - mean*mean + 1e-5f);
  float y[3][4]; float s2=0.f, ss2=0.f;
  #pragma unroll
  for (int t=0;t<3;++t){
    int c0 = lane*4 + t*256;
    float4 gg = *(const float4*)(g1 + c0);
    float4 bv = *(const float4*)(b1 + c0);
    y[t][0] = (v[t].x-mean)*inv*gg.x + bv.x;
    y[t][1] = (v[t].y-mean)*inv*gg.y + bv.y;
    y[t][2] = (v[t].z-mean)*inv*gg.z + bv.z;
    y[t][3] = (v[t].w-mean)*inv*gg.w + bv.w;
    float4 o = { y[t][0], y[t][1], y[t][2], y[t][3] };
    *(float4*)(out1 + ro + c0) = o;
    s2  += y[t][0]+y[t][1]+y[t][2]+y[t][3];
    ss2 += y[t][0]*y[t][0]+y[t][1]*y[t][1]+y[t][2]*y[t][2]+y[t][3]*y[t][3];
  }
  #pragma unroll
  for (int m=1;m<64;m<<=1){ s2 += __shfl_xor(s2,m); ss2 += __shfl_xor(ss2,m); }
  float mean2 = s2*(1.0f/768.0f);
  float inv2  = rsqrtf(ss2*(1.0f/768.0f) - mean2*mean2 + 1e-5f);
  #pragma unroll
  for (int t=0;t<3;++t){
    int c0 = lane*4 + t*256;
    float4 gg = *(const float4*)(g2 + c0);
    float4 bv = *(const float4*)(b2 + c0);
    f16x4 h4;
    h4.x = (f16)((y[t][0]-mean2)*inv2*gg.x + bv.x);
    h4.y = (f16)((y[t][1]-mean2)*inv2*gg.y + bv.y);
    h4.z = (f16)((y[t][2]-mean2)*inv2*gg.z + bv.z);
    h4.w = (f16)((y[t][3]-mean2)*inv2*gg.w + bv.w);
    *(f16x4*)(out2 + ro + c0) = h4;
  }
}

// ---------- h2 = H1 + O0 + O1 (written back f32); out = LN(h2) f16 ----------
__global__ __launch_bounds__(256) void lnadd3_k(
    const float* __restrict__ H1, const float* __restrict__ O0,
    const float* __restrict__ O1,
    const float* __restrict__ g, const float* __restrict__ bb,
    float* __restrict__ h2, f16* __restrict__ out)
{
  const int lane = threadIdx.x & 63;
  const size_t row = (size_t)blockIdx.x*4 + (threadIdx.x>>6);
  const size_t ro = row*D_DIM;
  float4 v[3]; float s=0.f, ss=0.f;
  #pragma unroll
  for (int t=0;t<3;++t){
    int c0 = lane*4 + t*256;
    float4 a = *(const float4*)(H1 + ro + c0);
    float4 b = *(const float4*)(O0 + ro + c0);
    float4 c = *(const float4*)(O1 + ro + c0);
    v[t].x = a.x+b.x+c.x; v[t].y = a.y+b.y+c.y;
    v[t].z = a.z+b.z+c.z; v[t].w = a.w+b.w+c.w;
    *(float4*)(h2 + ro + c0) = v[t];
    s  += v[t].x+v[t].y+v[t].z+v[t].w;
    ss += v[t].x*v[t].x+v[t].y*v[t].y+v[t].z*v[t].z+v[t].w*v[t].w;
  }
  #pragma unroll
  for (int m=1;m<64;m<<=1){ s += __shfl_xor(s,m); ss += __shfl_xor(ss,m); }
  float mean = s*(1.0f/768.0f);
  float inv  = rsqrtf(ss*(1.0f/768.0f) - mean*mean + 1e-5f);
  #pragma unroll
  for (int t=0;t<3;++t){
    int c0 = lane*4 + t*256;
    float4 gg = *(const float4*)(g + c0);
    float4 bv = *(const float4*)(bb + c0);
    f16x4 h4;
    h4.x = (f16)((v[t].x-mean)*inv*gg.x + bv.x);
    h4.y = (f16)((v[t].y-mean)*inv*gg.y + bv.y);
    h4.z = (f16)((v[t].z-mean)*inv*gg.z + bv.z);
    h4.w = (f16)((v[t].w-mean)*inv*gg.w + bv.w);
    *(f16x4*)(out + ro + c0) = h4;
  }
}

// ---------- final: v = H2 + sum_{z<8} W[z]; out1 = LN(v,lnf) f32; out2 = LN(out1,ns) f16 ----------
__global__ __launch_bounds__(256) void lnfin_k(
    const float* __restrict__ H2, const float* __restrict__ Wb,
    const float* __restrict__ g1, const float* __restrict__ b1,
    const float* __restrict__ g2, const float* __restrict__ b2,
    float* __restrict__ out1, f16* __restrict__ out2)
{
  const int lane = threadIdx.x & 63;
  const size_t row = (size_t)blockIdx.x*4 + (threadIdx.x>>6);
  const size_t ro = row*D_DIM;
  float4 v[3]; float s=0.f, ss=0.f;
  #pragma unroll
  for (int t=0;t<3;++t){
    int c0 = lane*4 + t*256;
    float4 a = *(const float4*)(H2 + ro + c0);
    #pragma unroll
    for (int z=0;z<8;++z){
      float4 b = *(const float4*)(Wb + (size_t)z*SLOTSZ + ro + c0);
      a.x+=b.x; a.y+=b.y; a.z+=b.z; a.w+=b.w;
    }
    v[t]=a;
    s  += v[t].x+v[t].y+v[t].z+v[t].w;
    ss += v[t].x*v[t].x+v[t].y*v[t].y+v[t].z*v[t].z+v[t].w*v[t].w;
  }
  #pragma unroll
  for (int m=1;m<64;m<<=1){ s += __shfl_xor(s,m); ss += __shfl_xor(ss,m); }
  float mean = s*(1.0f/768.0f);
  float inv  = rsqrtf(ss*(1.0f/768.0f) - mean*mean + 1e-5f);
  float y[3][4]; float s2=0.f, ss2=0.f;
  #pragma unroll
  for (int t=0;t<3;++t){
    int c0 = lane*4 + t*256;
    float4 gg = *(const float4*)(g1 + c0);
    float4 bv = *(const float4*)(b1 + c0);
    y[t][0] = (v[t].x-mean)*inv*gg.x + bv.x;
    y[t][1] = (v[t].y-mean)*inv*gg.y + bv.y;
    y[t][2] = (v[t].z-mean)*inv*gg.z + bv.z;
    y[t][3] = (v[t].w-mean)*inv*gg.w + bv.w;
    float4 o = { y[t][0], y[t][1], y[t][2], y[t][3] };
    *(float4*)(out1 + ro + c0) = o;
    s2  += y[t][0]+y[t][1]+y[t][2]+y[t][3];
    ss2 += y[t][0]*y[t][0]+y[t][1]*y[t][1]+y[t][2]*y[t][2]+y[t][3]*y[t][3];
  }
  #pragma unroll
  for (int m=1;m<64;m<<=1){ s2 += __shfl_xor(s2,m); ss2 += __shfl_xor(ss2,m); }
  float mean2 = s2*(1.0f/768.0f);
  float inv2  = rsqrtf(ss2*(1.0f/768.0f) - mean2*mean2 + 1e-5f);
  #pragma unroll
  for (int t=0;t<3;++t){
    int c0 = lane*4 + t*256;
    float4 gg = *(const float4*)(g2 + c0);
    float4 bv = *(const float4*)(b2 + c0);
    f16x4 h4;
    h4.x = (f16)((y[t][0]-mean2)*inv2*gg.x + bv.x);
    h4.y = (f16)((y[t][1]-mean2)*inv2*gg.y + bv.y);
    h4.z = (f16)((y[t][2]-mean2)*inv2*gg.z + bv.z);
    h4.w = (f16)((y[t][3]-mean2)*inv2*gg.w + bv.w);
    *(f16x4*)(out2 + ro + c0) = h4;
  }
}

// ---------- slots init + LN(ns) fused ----------
__global__ __launch_bounds__(256) void slotsinit_k(
    const float* __restrict__ noise, const float* __restrict__ mu,
    const float* __restrict__ ls,
    const float* __restrict__ nsg, const float* __restrict__ nsb,
    float* __restrict__ slots, f16* __restrict__ tmp2)
{
  const int lane = threadIdx.x & 63;
  const size_t row = (size_t)blockIdx.x*4 + (threadIdx.x>>6);
  float4 v[3]; float s=0.f, ss=0.f;
  #pragma unroll
  for (int t=0;t<3;++t){
    int c0 = lane*4 + t*256;
    float4 nz = *(const float4*)(noise + row*D_DIM + c0);
    float4 m4 = *(const float4*)(mu + c0);
    float4 l4 = *(const float4*)(ls + c0);
    v[t].x = m4.x + __expf(l4.x)*nz.x;
    v[t].y = m4.y + __expf(l4.y)*nz.y;
    v[t].z = m4.z + __expf(l4.z)*nz.z;
    v[t].w = m4.w + __expf(l4.w)*nz.w;
    *(float4*)(slots + row*D_DIM + c0) = v[t];
    s  += v[t].x+v[t].y+v[t].z+v[t].w;
    ss += v[t].x*v[t].x+v[t].y*v[t].y+v[t].z*v[t].z+v[t].w*v[t].w;
  }
  #pragma unroll
  for (int m=1;m<64;m<<=1){ s += __shfl_xor(s,m); ss += __shfl_xor(ss,m); }
  float mean = s*(1.0f/768.0f);
  float inv  = rsqrtf(ss*(1.0f/768.0f) - mean*mean + 1e-5f);
  #pragma unroll
  for (int t=0;t<3;++t){
    int c0 = lane*4 + t*256;
    float4 gg = *(const float4*)(nsg + c0);
    float4 bv = *(const float4*)(nsb + c0);
    f16x4 h4;
    h4.x = (f16)((v[t].x-mean)*inv*gg.x + bv.x);
    h4.y = (f16)((v[t].y-mean)*inv*gg.y + bv.y);
    h4.z = (f16)((v[t].z-mean)*inv*gg.z + bv.z);
    h4.w = (f16)((v[t].w-mean)*inv*gg.w + bv.w);
    *(f16x4*)(tmp2 + row*D_DIM + c0) = h4;
  }
}

// ---------- encoder self-attention (qkv from 3 f32 split-K partials) ----------
__global__ __launch_bounds__(256) void encattn_k(
    const float* __restrict__ A0, const float* __restrict__ A1,
    const float* __restrict__ A2,
    f16* __restrict__ O)
{
  __shared__ float qs[16][68], ks[16][68], vs[16][68], ps[16][20];
  const int b = blockIdx.x, h = blockIdx.y;
  const int tid = threadIdx.x;
  {
    int i = tid>>4, dd=(tid&15)*4;
    size_t base = ((size_t)(b*NSLOT+i))*1536 + h*64 + dd;
    float4 q0 = *(const float4*)(A0+base);
    float4 q1 = *(const float4*)(A1+base);
    float4 q2 = *(const float4*)(A2+base);
    float4 k0 = *(const float4*)(A0+base+512);
    float4 k1 = *(const float4*)(A1+base+512);
    float4 k2 = *(const float4*)(A2+base+512);
    float4 u0 = *(const float4*)(A0+base+1024);
    float4 u1 = *(const float4*)(A1+base+1024);
    float4 u2 = *(const float4*)(A2+base+1024);
    float4 fq = { q0.x+q1.x+q2.x, q0.y+q1.y+q2.y, q0.z+q1.z+q2.z, q0.w+q1.w+q2.w };
    float4 fk = { k0.x+k1.x+k2.x, k0.y+k1.y+k2.y, k0.z+k1.z+k2.z, k0.w+k1.w+k2.w };
    float4 fv = { u0.x+u1.x+u2.x, u0.y+u1.y+u2.y, u0.z+u1.z+u2.z, u0.w+u1.w+u2.w };
    *(float4*)&qs[i][dd]=fq; *(float4*)&ks[i][dd]=fk; *(float4*)&vs[i][dd]=fv;
  }
  __syncthreads();
  {
    int i = tid>>4, j = tid&15;
    float s=0.f;
    #pragma unroll 8
    for (int d=0; d<64; ++d) s += qs[i][d]*ks[j][d];
    ps[i][j] = s*SCALE_H;
  }
  __syncthreads();
  if (tid < 16){
    int i = tid;
    float mx=-1e30f;
    #pragma unroll
    for (int j=0;j<16;++j) mx = fmaxf(mx, ps[i][j]);
    float sm=0.f;
    #pragma unroll
    for (int j=0;j<16;++j){ float e=__expf(ps[i][j]-mx); ps[i][j]=e; sm+=e; }
    float inv=1.0f/sm;
    #pragma unroll
    for (int j=0;j<16;++j) ps[i][j]*=inv;
  }
  __syncthreads();
  {
    int i = tid>>4, dq=(tid&15)*4;
    float a0=0,a1=0,a2=0,a3=0;
    #pragma unroll
    for (int j=0;j<16;++j){
      float p = ps[i][j];
      a0+=p*vs[j][dq+0]; a1+=p*vs[j][dq+1]; a2+=p*vs[j][dq+2]; a3+=p*vs[j][dq+3];
    }
    size_t base = ((size_t)(b*NSLOT+i))*HDIM + h*64 + dq;
    O[base+0]=(f16)a0; O[base+1]=(f16)a1; O[base+2]=(f16)a2; O[base+3]=(f16)a3;
  }
}

// ---------- f16 transpose: out[C][R] = in[R][C] ----------
__global__ __launch_bounds__(256) void transp_k(
    const f16* __restrict__ in, f16* __restrict__ out, int R, int C)
{
  __shared__ f16 T[64][72];
  const int m0 = blockIdx.x*64, d0 = blockIdx.y*64;
  const int tid = threadIdx.x;
  {
    int r = tid>>2, c = (tid&3)*16;
    const f16* p = in + (size_t)(m0+r)*C + d0 + c;
    *(f16x8*)&T[r][c]   = *(const f16x8*)p;
    *(f16x8*)&T[r][c+8] = *(const f16x8*)(p+8);
  }
  __syncthreads();
  {
    int dd = tid>>2, mq = (tid&3)*16;
    f16 v[16];
    #pragma unroll
    for (int e=0;e<16;++e) v[e] = T[mq+e][dd];
    f16* p = out + (size_t)(d0+dd)*R + m0 + mq;
    *(f16x8*)p     = *(f16x8*)&v[0];
    *(f16x8*)(p+8) = *(f16x8*)&v[8];
  }
}

// ---------- all weight casts/transposes in ONE kernel ----------
__global__ __launch_bounds__(256) void prep_k(
    const float* __restrict__ Wv,   const float* __restrict__ Wq_a,
    const float* __restrict__ Wk_a, const float* __restrict__ Wv_a,
    const float* __restrict__ Wo_a, const float* __restrict__ W1,
    const float* __restrict__ W2,   const float* __restrict__ Wk,
    const float* __restrict__ Wq,
    f16* __restrict__ WvT, f16* __restrict__ WqkvT, f16* __restrict__ WoaT,
    f16* __restrict__ W1T, f16* __restrict__ W2T,
    f16* __restrict__ Wkf, f16* __restrict__ Wqf)
{
  __shared__ float t[32][33];
  int bid = blockIdx.x;
  const float* src; f16* dst; int R, C; bool tr = true;
  if      (bid < 576)  {              src=Wv;   dst=WvT;             R=768;  C=768; }
  else if (bid < 960)  { bid-=576;    src=Wq_a; dst=WqkvT;           R=768;  C=512; }
  else if (bid < 1344) { bid-=960;    src=Wk_a; dst=WqkvT+512*768;   R=768;  C=512; }
  else if (bid < 1728) { bid-=1344;   src=Wv_a; dst=WqkvT+1024*768;  R=768;  C=512; }
  else if (bid < 2112) { bid-=1728;   src=Wo_a; dst=WoaT;            R=512;  C=768; }
  else if (bid < 6720) { bid-=2112;   src=W1;   dst=W1T;             R=768;  C=6144; }
  else if (bid < 9024) { bid-=6720;   src=W2;   dst=W2T;             R=3072; C=768; }
  else if (bid < 9600) { bid-=9024;   src=Wk;   dst=Wkf;             R=768;  C=768; tr=false; }
  else                 { bid-=9600;   src=Wq;   dst=Wqf;             R=768;  C=768; tr=false; }
  const int tpr = C/32;
  const int r0 = (bid / tpr)*32, c0 = (bid % tpr)*32;
  const int lc = threadIdx.x & 31, g8 = threadIdx.x >> 5;
  if (tr){
    #pragma unroll
    for (int s=0;s<4;++s){
      int r = g8*4 + s;
      t[r][lc] = src[(size_t)(r0+r)*C + c0+lc];
    }
    __syncthreads();
    #pragma unroll
    for (int s=0;s<4;++s){
      int c = g8*4 + s;
      dst[(size_t)(c0+c)*R + r0+lc] = (f16)t[lc][c];
    }
  } else {
    #pragma unroll
    for (int s=0;s<4;++s){
      int r = g8*4 + s;
      dst[(size_t)(r0+r)*C + c0+lc] = (f16)src[(size_t)(r0+r)*C + c0+lc];
    }
  }
}

// ---------- attn_map output (rowsum inline) ----------
__global__ __launch_bounds__(256) void attnout_k(
    const f16* __restrict__ attn, const float* __restrict__ rsPart,
    float* __restrict__ out)
{
  __shared__ float rsum[16];
  const int bid = blockIdx.x, tid = threadIdx.x;
  const int b = bid >> 6;
  if (tid < 16){
    float s = 0.f;
    #pragma unroll
    for (int jt=0;jt<16;++jt) s += rsPart[(size_t)((b*16+jt)<<4) + tid];
    rsum[tid] = s;
  }
  __syncthreads();
  int idx = bid*256 + tid;
  int i = idx & 15;
  int j = (idx >> 4) & 1023;
  out[idx] = (float)attn[((size_t)(b*NSLOT)+i)*NTOK + j] / rsum[i];
}

extern "C" void kernel_launch(void* const* d_in, const int* in_sizes, int n_in,
                              void* d_out, int out_size, void* d_ws, size_t ws_size,
                              hipStream_t stream) {
  const float* x        = (const float*)d_in[0];
  const float* noise    = (const float*)d_in[1];
  const float* init_mu  = (const float*)d_in[2];
  const float* init_ls  = (const float*)d_in[3];
  const float* Wk       = (const float*)d_in[4];
  const float* Wv       = (const float*)d_in[5];
  const float* Wq       = (const float*)d_in[6];
  const float* ni_g     = (const float*)d_in[7];
  const float* ni_b     = (const float*)d_in[8];
  const float* ns_g     = (const float*)d_in[9];
  const float* ns_b     = (const float*)d_in[10];
  const float* nica_g   = (const float*)d_in[11];
  const float* nica_b   = (const float*)d_in[12];
  const float* ln1_g    = (const float*)d_in[13];
  const float* ln1_b    = (const float*)d_in[14];
  const float* Wq_a     = (const float*)d_in[15];
  const float* Wk_a     = (const float*)d_in[16];
  const float* Wv_a     = (const float*)d_in[17];
  const float* Wo_a     = (const float*)d_in[18];
  const float* ln2_g    = (const float*)d_in[19];
  const float* ln2_b    = (const float*)d_in[20];
  const float* W1       = (const float*)d_in[21];
  const float* W2       = (const float*)d_in[22];
  const float* lnf_g    = (const float*)d_in[23];
  const float* lnf_b    = (const float*)d_in[24];

  char* w = (char*)d_ws;
  size_t off = 0;
  auto alloc = [&](size_t bytes)->char*{
    char* p = w + off; off += (bytes + 255) & ~(size_t)255; return p;
  };
  f16* xn_h  = (f16*)alloc((size_t)NTOT*D_DIM*2);
  f16* xnT_h = (f16*)alloc((size_t)D_DIM*NTOT*2);
  f16* Wkf   = (f16*)alloc((size_t)768*768*2);
  f16* Wqf   = (f16*)alloc((size_t)768*768*2);
  f16* BtQK  = (f16*)alloc((size_t)768*768*2);
  f16* WvT   = (f16*)alloc((size_t)768*768*2);
  f16* WqkvT = (f16*)alloc((size_t)1536*768*2);
  f16* WoaT  = (f16*)alloc((size_t)768*512*2);
  f16* W1T   = (f16*)alloc((size_t)6144*768*2);
  f16* W2T   = (f16*)alloc((size_t)768*3072*2);
  float* slots = (float*)alloc(SLOTSZ*4);
  float* hbuf  = (float*)alloc(SLOTSZ*4);
  float* h2buf = (float*)alloc(SLOTSZ*4);
  float* q32   = (float*)alloc((size_t)3*SLOTSZ*4);
  float* upd3  = (float*)alloc((size_t)3*SLOTSZ*4);
  float* qkv32 = (float*)alloc((size_t)3*512*1536*4);
  float* oo    = (float*)alloc((size_t)2*SLOTSZ*4);
  float* ww    = (float*)alloc((size_t)8*SLOTSZ*4);
  f16* tmp_h  = (f16*)alloc(SLOTSZ*2);
  f16* tmp2_h = (f16*)alloc(SLOTSZ*2);
  f16* t_h    = (f16*)alloc(SLOTSZ*2);
  f16* o_h    = (f16*)alloc(512*512*2);
  f16* act_h  = (f16*)alloc((size_t)512*3072*2);
  f16* attn_h = (f16*)alloc((size_t)NB*NSLOT*NTOK*2);
  float* rsPart = (float*)alloc((size_t)32*16*16*4);

  // weight prep: all casts/transposes in one launch
  prep_k<<<10176, 256, 0, stream>>>(Wv, Wq_a, Wk_a, Wv_a, Wo_a, W1, W2, Wk, Wq,
                                    WvT, WqkvT, WoaT, W1T, W2T, Wkf, Wqf);

  // BtQK[f][e] = sum_d Wk[f][d] * Wq[e][d]
  mgemm64_k<1><<<dim3(12, 12, 1), 256, 0, stream>>>(Wkf, Wqf, BtQK, 768, 768, 768, 768);

  // xn = LN(x); xnT = xn^T
  lnw_k<<<NTOT/4, 256, 0, stream>>>(x, ni_g, ni_b, xn_h);
  transp_k<<<dim3(NTOT/64, D_DIM/64), 256, 0, stream>>>(xn_h, xnT_h, NTOT, D_DIM);

  // slots = mu + exp(ls)*noise; tmp2 = LN(slots, ns)
  slotsinit_k<<<128, 256, 0, stream>>>(noise, init_mu, init_ls, ns_g, ns_b,
                                       slots, tmp2_h);

  for (int it=0; it<4; ++it){
    // q_eff partials = LN(slots,ns) @ (Wq Wk^T), split-K=3 multi-buffer
    mgemm64_k<3><<<dim3(8, 12, 3), 256, 0, stream>>>(tmp2_h, BtQK, q32, 512, 768, 768, 256);
    // dots = (q0+q1+q2) @ xn^T + inverted softmax
    dots_k<<<dim3(NB, 16), 256, 0, stream>>>(q32, q32+SLOTSZ, q32+2*SLOTSZ,
                                             xn_h, attn_h, rsPart);
    // t = (attn @ xn) / rowsum
    attnv_k<<<dim3(NB, 12), 256, 0, stream>>>(attn_h, rsPart, xnT_h, t_h);
    // upd partials = t @ Wv, split-K=3 multi-buffer
    mgemm64_k<3><<<dim3(8, 12, 3), 256, 0, stream>>>(t_h, WvT, upd3, 512, 768, 768, 256);
    // hbuf = LN(slots+u0+u1+u2, nica); tmp = LN(hbuf, ln1)
    lnln_res_k<<<128, 256, 0, stream>>>(slots, upd3, upd3+SLOTSZ, upd3+2*SLOTSZ,
                                        nica_g, nica_b, ln1_g, ln1_b, hbuf, tmp_h);
    // qkv partials = a @ [Wq_a|Wk_a|Wv_a], split-K=3 multi-buffer
    mgemm64_k<3><<<dim3(8, 24, 3), 256, 0, stream>>>(tmp_h, WqkvT, qkv32, 512, 1536, 768, 256);
    encattn_k<<<dim3(NB, 8), 256, 0, stream>>>(qkv32, qkv32+512*1536, qkv32+2*512*1536, o_h);
    // oo = o @ Wo_a (split-K=2 multi-buffer)
    mgemm64_k<3><<<dim3(8, 12, 2), 256, 0, stream>>>(o_h, WoaT, oo, 512, 768, 512, 256);
    // h2 = hbuf+oo0+oo1 (stored); tmp = LN(h2, ln2)
    lnadd3_k<<<128, 256, 0, stream>>>(hbuf, oo, oo+SLOTSZ, ln2_g, ln2_b, h2buf, tmp_h);
    // act = glu(f @ W1)
    w1glu_k<<<dim3(8, 48), 256, 0, stream>>>(tmp_h, W1T, act_h, 512);
    // ww = act @ W2 (split-K=8 multi-buffer)
    mgemm64_k<3><<<dim3(8, 12, 8), 256, 0, stream>>>(act_h, W2T, ww, 512, 768, 3072, 384);
    // slots = LN(h2+Σww, lnf) [last iter: straight to d_out]; tmp2 = LN(slots, ns)
    float* out1 = (it==3) ? (float*)d_out : slots;
    lnfin_k<<<128, 256, 0, stream>>>(h2buf, ww, lnf_g, lnf_b, ns_g, ns_b,
                                     out1, tmp2_h);
  }

  attnout_k<<<NB*NTOK*NSLOT/256, 256, 0, stream>>>(attn_h, rsPart, (float*)d_out + 512*768);
}

// Round 5
// 627.048 us; speedup vs baseline: 1.0123x; 1.0123x over previous
//
#include <hip/hip_runtime.h>
#include <hip/hip_bf16.h>
#include <stdint.h>

typedef _Float16 f16;
typedef __attribute__((ext_vector_type(8))) _Float16 f16x8;
typedef __attribute__((ext_vector_type(4))) _Float16 f16x4;
typedef __attribute__((ext_vector_type(4))) float f32x4;

#define GLOBAL_AS __attribute__((address_space(1)))
#define LDS_AS __attribute__((address_space(3)))

#define D_DIM 768
#define NTOK 1024
#define NSLOT 16
#define NB 32
#define NTOT (NB*NTOK)   // 32768
#define HDIM 512
#define INNER 3072
#define SCALE_D 0.03608439182435161f   // 768^-0.5
#define SCALE_H 0.125f                 // 64^-0.5

// ---------- MFMA GEMM 64x64, BK=256 (8 panels, one drain per 256-K step), split-K ----------
// OUT: 0 = f32 store, 1 = f16 store, 2 = f32 atomicAdd.  Kc % 256 == 0.
template<int OUT>
__global__ __launch_bounds__(256) void mgemm64_k(
    const f16* __restrict__ A, const f16* __restrict__ Bt,
    void* __restrict__ Cout, int M, int N, int K, int Kc)
{
  __shared__ __align__(16) f16 As[64*256];
  __shared__ __align__(16) f16 Bs[64*256];
  const int tid = threadIdx.x;
  const int lane = tid & 63;
  const int wave = tid >> 6;
  const int m0 = blockIdx.x*64, n0 = blockIdx.y*64;
  const int kbeg = blockIdx.z * Kc;
  const int wm = (wave>>1)*32, wn = (wave&1)*32;
  const int quad = lane>>4, l16 = lane&15;

  const int sr = tid>>2;
  const int sc = (tid&3)*8;
  const f16* gA = A  + (size_t)(m0+sr)*K + kbeg + sc;
  const f16* gB = Bt + (size_t)(n0+sr)*K + kbeg + sc;
  LDS_AS f16* lA = (LDS_AS f16*)&As[(size_t)tid*8];
  LDS_AS f16* lB = (LDS_AS f16*)&Bs[(size_t)tid*8];

  const f16* fA0 = &As[(wm + l16)*32 + quad*8];
  const f16* fB0 = &Bs[(wn + l16)*32 + quad*8];

  f32x4 acc[2][2] = {};

  for (int k0 = 0; k0 < Kc; k0 += 256){
    #pragma unroll
    for (int p=0;p<8;++p){
      __builtin_amdgcn_global_load_lds((const GLOBAL_AS void*)(gA + k0 + p*32),
                                       (LDS_AS void*)(lA + (size_t)p*2048), 16, 0, 0);
      __builtin_amdgcn_global_load_lds((const GLOBAL_AS void*)(gB + k0 + p*32),
                                       (LDS_AS void*)(lB + (size_t)p*2048), 16, 0, 0);
    }
    __syncthreads();
    #pragma unroll
    for (int p=0;p<8;++p){
      f16x8 a0 = *(const f16x8*)(fA0 + p*2048);
      f16x8 a1 = *(const f16x8*)(fA0 + p*2048 + 16*32);
      f16x8 b0 = *(const f16x8*)(fB0 + p*2048);
      f16x8 b1 = *(const f16x8*)(fB0 + p*2048 + 16*32);
      acc[0][0] = __builtin_amdgcn_mfma_f32_16x16x32_f16(a0,b0,acc[0][0],0,0,0);
      acc[0][1] = __builtin_amdgcn_mfma_f32_16x16x32_f16(a0,b1,acc[0][1],0,0,0);
      acc[1][0] = __builtin_amdgcn_mfma_f32_16x16x32_f16(a1,b0,acc[1][0],0,0,0);
      acc[1][1] = __builtin_amdgcn_mfma_f32_16x16x32_f16(a1,b1,acc[1][1],0,0,0);
    }
    __syncthreads();
  }
  #pragma unroll
  for (int mt=0;mt<2;++mt){
    #pragma unroll
    for (int nt=0;nt<2;++nt){
      int gm = m0 + wm + mt*16 + quad*4;
      int gn = n0 + wn + nt*16 + l16;
      #pragma unroll
      for (int r=0;r<4;++r){
        float c = acc[mt][nt][r];
        size_t idx = (size_t)(gm+r)*N + gn;
        if (OUT==0)      ((float*)Cout)[idx] = c;
        else if (OUT==1) ((f16*)Cout)[idx] = (f16)c;
        else             atomicAdd(&((float*)Cout)[idx], c);
      }
    }
  }
}

// ---------- W1 + GLU fused (BK=128: 3 LDS buffers, keep 3 blocks/CU) ----------
__global__ __launch_bounds__(256) void w1glu_k(
    const f16* __restrict__ A, const f16* __restrict__ W1T,
    f16* __restrict__ act, int M)
{
  __shared__ __align__(16) f16 As[64*128];
  __shared__ __align__(16) f16 Bu[64*128];
  __shared__ __align__(16) f16 Bg[64*128];
  const int K = 768;
  const int tid = threadIdx.x;
  const int lane = tid & 63;
  const int wave = tid >> 6;
  const int m0 = blockIdx.x*64, n0 = blockIdx.y*64;
  const int wm = (wave>>1)*32, wn = (wave&1)*32;
  const int quad = lane>>4, l16 = lane&15;

  const int sr = tid>>2;
  const int sc = (tid&3)*8;
  const f16* gA  = A   + (size_t)(m0+sr)*K + sc;
  const f16* gBu = W1T + (size_t)(n0+sr)*K + sc;
  const f16* gBg = W1T + (size_t)(3072+n0+sr)*K + sc;
  LDS_AS f16* lA  = (LDS_AS f16*)&As[(size_t)tid*8];
  LDS_AS f16* lBu = (LDS_AS f16*)&Bu[(size_t)tid*8];
  LDS_AS f16* lBg = (LDS_AS f16*)&Bg[(size_t)tid*8];

  const f16* fA0 = &As[(wm + l16)*32 + quad*8];
  const f16* fU0 = &Bu[(wn + l16)*32 + quad*8];
  const f16* fG0 = &Bg[(wn + l16)*32 + quad*8];

  f32x4 accU[2][2] = {};
  f32x4 accG[2][2] = {};

  for (int k0 = 0; k0 < K; k0 += 128){
    #pragma unroll
    for (int p=0;p<4;++p){
      __builtin_amdgcn_global_load_lds((const GLOBAL_AS void*)(gA  + k0 + p*32),
                                       (LDS_AS void*)(lA  + (size_t)p*2048), 16, 0, 0);
      __builtin_amdgcn_global_load_lds((const GLOBAL_AS void*)(gBu + k0 + p*32),
                                       (LDS_AS void*)(lBu + (size_t)p*2048), 16, 0, 0);
      __builtin_amdgcn_global_load_lds((const GLOBAL_AS void*)(gBg + k0 + p*32),
                                       (LDS_AS void*)(lBg + (size_t)p*2048), 16, 0, 0);
    }
    __syncthreads();
    #pragma unroll
    for (int p=0;p<4;++p){
      f16x8 a0 = *(const f16x8*)(fA0 + p*2048);
      f16x8 a1 = *(const f16x8*)(fA0 + p*2048 + 16*32);
      f16x8 u0 = *(const f16x8*)(fU0 + p*2048);
      f16x8 u1 = *(const f16x8*)(fU0 + p*2048 + 16*32);
      f16x8 g0 = *(const f16x8*)(fG0 + p*2048);
      f16x8 g1 = *(const f16x8*)(fG0 + p*2048 + 16*32);
      accU[0][0] = __builtin_amdgcn_mfma_f32_16x16x32_f16(a0,u0,accU[0][0],0,0,0);
      accU[0][1] = __builtin_amdgcn_mfma_f32_16x16x32_f16(a0,u1,accU[0][1],0,0,0);
      accU[1][0] = __builtin_amdgcn_mfma_f32_16x16x32_f16(a1,u0,accU[1][0],0,0,0);
      accU[1][1] = __builtin_amdgcn_mfma_f32_16x16x32_f16(a1,u1,accU[1][1],0,0,0);
      accG[0][0] = __builtin_amdgcn_mfma_f32_16x16x32_f16(a0,g0,accG[0][0],0,0,0);
      accG[0][1] = __builtin_amdgcn_mfma_f32_16x16x32_f16(a0,g1,accG[0][1],0,0,0);
      accG[1][0] = __builtin_amdgcn_mfma_f32_16x16x32_f16(a1,g0,accG[1][0],0,0,0);
      accG[1][1] = __builtin_amdgcn_mfma_f32_16x16x32_f16(a1,g1,accG[1][1],0,0,0);
    }
    __syncthreads();
  }
  #pragma unroll
  for (int mt=0;mt<2;++mt){
    #pragma unroll
    for (int nt=0;nt<2;++nt){
      int gm = m0 + wm + mt*16 + quad*4;
      int gn = n0 + wn + nt*16 + l16;
      #pragma unroll
      for (int r=0;r<4;++r){
        float u = accU[mt][nt][r];
        float g = accG[mt][nt][r];
        float sg = g / (1.0f + __expf(-g));
        act[(size_t)(gm+r)*INNER + gn] = (f16)(u*sg);
      }
    }
  }
}

// ---------- MFMA dots (q_eff @ xn^T) + inverted softmax + EPS + partial rowsum ----------
// BK=256: 3 drains instead of 6.
__global__ __launch_bounds__(256) void dots_k(
    const f16* __restrict__ Q,    // [32,16,768] q_eff
    const f16* __restrict__ Xn,   // [32768,768]
    f16* __restrict__ attn,       // [32,16,1024] f16
    float* __restrict__ rsPart)   // [32][16 jt][16 i]
{
  __shared__ __align__(16) f16 qf[16*768];    // A-frag layout, 24 KB
  __shared__ __align__(16) f16 ks[64*256];    // 8 panels [64][32], 32 KB
  __shared__ float rpart[4][16];
  const int b = blockIdx.x, jt = blockIdx.y;
  const int tid = threadIdx.x;
  const int lane = tid & 63;
  const int w = tid >> 6;
  const int quad = lane>>4, l16 = lane&15;

  #pragma unroll
  for (int c=0;c<6;++c){
    int p = c*256 + tid;
    int ki = p >> 6, qd = (p >> 4) & 3, rw = p & 15;
    f16x8 v = *(const f16x8*)(Q + ((size_t)(b*NSLOT+rw))*D_DIM + ki*32 + qd*8);
    *(f16x8*)&qf[(size_t)p*8] = v;
  }

  const f16* gK = Xn + ((size_t)(b*NTOK + jt*64 + (tid>>2)))*D_DIM + (tid&3)*8;
  LDS_AS f16* lK = (LDS_AS f16*)&ks[(size_t)tid*8];

  f32x4 acc = {};
  for (int it=0; it<3; ++it){
    #pragma unroll
    for (int p=0;p<8;++p)
      __builtin_amdgcn_global_load_lds((const GLOBAL_AS void*)(gK + it*256 + p*32),
                                       (LDS_AS void*)(lK + (size_t)p*2048), 16, 0, 0);
    __syncthreads();
    #pragma unroll
    for (int p=0;p<8;++p){
      f16x8 a  = *(const f16x8*)&qf[(((size_t)(it*8+p)*4 + quad)*16 + l16)*8];
      f16x8 bf = *(const f16x8*)&ks[(size_t)p*2048 + (w*16+l16)*32 + quad*8];
      acc = __builtin_amdgcn_mfma_f32_16x16x32_f16(a, bf, acc, 0, 0, 0);
    }
    __syncthreads();
  }

  float v0 = acc[0]*SCALE_D, v1 = acc[1]*SCALE_D, v2 = acc[2]*SCALE_D, v3 = acc[3]*SCALE_D;
  float mx = fmaxf(fmaxf(v0,v1), fmaxf(v2,v3));
  mx = fmaxf(mx, __shfl_xor(mx, 16));
  mx = fmaxf(mx, __shfl_xor(mx, 32));
  float e0 = __expf(v0-mx), e1 = __expf(v1-mx), e2 = __expf(v2-mx), e3 = __expf(v3-mx);
  float s = e0+e1+e2+e3;
  s += __shfl_xor(s, 16);
  s += __shfl_xor(s, 32);
  float inv = 1.0f/s;
  float a0 = e0*inv + 1e-8f, a1 = e1*inv + 1e-8f, a2 = e2*inv + 1e-8f, a3 = e3*inv + 1e-8f;

  int jcol = jt*64 + w*16 + l16;
  int ibase = b*NSLOT + quad*4;
  attn[(size_t)(ibase+0)*NTOK + jcol] = (f16)a0;
  attn[(size_t)(ibase+1)*NTOK + jcol] = (f16)a1;
  attn[(size_t)(ibase+2)*NTOK + jcol] = (f16)a2;
  attn[(size_t)(ibase+3)*NTOK + jcol] = (f16)a3;

  float t0=a0, t1=a1, t2=a2, t3=a3;
  #pragma unroll
  for (int m=1;m<16;m<<=1){
    t0 += __shfl_xor(t0, m);
    t1 += __shfl_xor(t1, m);
    t2 += __shfl_xor(t2, m);
    t3 += __shfl_xor(t3, m);
  }
  if (l16 == 0){
    rpart[w][quad*4+0] = t0;
    rpart[w][quad*4+1] = t1;
    rpart[w][quad*4+2] = t2;
    rpart[w][quad*4+3] = t3;
  }
  __syncthreads();
  if (tid < 16){
    float ss = rpart[0][tid] + rpart[1][tid] + rpart[2][tid] + rpart[3][tid];
    rsPart[(size_t)((b*16 + jt)<<4) + tid] = ss;
  }
}

// ---------- t = (attn @ xn) / rowsum via MFMA on xnT; BK=256: 4 drains ----------
__global__ __launch_bounds__(256) void attnv_k(
    const f16* __restrict__ attn,   // [32,16,1024] f16
    const float* __restrict__ rsPart,
    const f16* __restrict__ XnT,    // [768, 32768]
    f16* __restrict__ t_out)        // [32,16,768] f16
{
  __shared__ __align__(16) f16 Asl[16*256];
  __shared__ __align__(16) f16 Bsl[64*256];
  __shared__ float rsum[16];
  const int b = blockIdx.x, d0 = blockIdx.y*64;
  const int tid = threadIdx.x;
  const int lane = tid & 63;
  const int w = tid >> 6;
  const int quad = lane>>4, l16 = lane&15;

  if (tid < 16){
    float s = 0.f;
    #pragma unroll
    for (int jt=0;jt<16;++jt) s += rsPart[(size_t)((b*16 + jt)<<4) + tid];
    rsum[tid] = s;
  }

  const int pa = tid>>6, ta = tid&63;
  const f16* gA = attn + ((size_t)(b*NSLOT + (ta>>2)))*NTOK + (ta&3)*8;
  const f16* gB = XnT + ((size_t)(d0 + (tid>>2)))*NTOT + b*NTOK + (tid&3)*8;
  LDS_AS f16* lB = (LDS_AS f16*)&Bsl[(size_t)tid*8];

  f32x4 acc = {};
  for (int it=0; it<4; ++it){
    #pragma unroll
    for (int q=0;q<2;++q){
      int pq = pa*2 + q;
      __builtin_amdgcn_global_load_lds((const GLOBAL_AS void*)(gA + it*256 + pq*32),
                                       (LDS_AS void*)((LDS_AS f16*)&Asl[(size_t)pq*512 + ta*8]), 16, 0, 0);
    }
    #pragma unroll
    for (int p=0;p<8;++p)
      __builtin_amdgcn_global_load_lds((const GLOBAL_AS void*)(gB + it*256 + p*32),
                                       (LDS_AS void*)(lB + (size_t)p*2048), 16, 0, 0);
    __syncthreads();
    #pragma unroll
    for (int p=0;p<8;++p){
      f16x8 a  = *(const f16x8*)&Asl[(size_t)p*512 + l16*32 + quad*8];
      f16x8 bf = *(const f16x8*)&Bsl[(size_t)p*2048 + (w*16+l16)*32 + quad*8];
      acc = __builtin_amdgcn_mfma_f32_16x16x32_f16(a, bf, acc, 0, 0, 0);
    }
    __syncthreads();
  }
  int dcol = d0 + w*16 + l16;
  #pragma unroll
  for (int r=0;r<4;++r){
    int i = quad*4 + r;
    t_out[(size_t)(b*NSLOT + i)*D_DIM + dcol] = (f16)(acc[r] / rsum[i]);
  }
}

// ---------- wave-per-row LN (4 rows/block), f16 out ----------
__global__ __launch_bounds__(256) void lnw_k(
    const float* __restrict__ X,
    const float* __restrict__ g, const float* __restrict__ bb,
    f16* __restrict__ out)
{
  const int lane = threadIdx.x & 63;
  const size_t row = (size_t)blockIdx.x*4 + (threadIdx.x>>6);
  const float* x = X + row*D_DIM;
  float4 v[3]; float s=0.f, ss=0.f;
  #pragma unroll
  for (int t=0;t<3;++t){
    v[t] = *(const float4*)(x + lane*4 + t*256);
    s  += v[t].x+v[t].y+v[t].z+v[t].w;
    ss += v[t].x*v[t].x+v[t].y*v[t].y+v[t].z*v[t].z+v[t].w*v[t].w;
  }
  #pragma unroll
  for (int m=1;m<64;m<<=1){ s += __shfl_xor(s,m); ss += __shfl_xor(ss,m); }
  float mean = s*(1.0f/768.0f);
  float inv  = rsqrtf(ss*(1.0f/768.0f) - mean*mean + 1e-5f);
  #pragma unroll
  for (int t=0;t<3;++t){
    int c0 = lane*4 + t*256;
    float4 gg = *(const float4*)(g + c0);
    float4 bv = *(const float4*)(bb + c0);
    f16x4 h4;
    h4.x = (f16)((v[t].x-mean)*inv*gg.x + bv.x);
    h4.y = (f16)((v[t].y-mean)*inv*gg.y + bv.y);
    h4.z = (f16)((v[t].z-mean)*inv*gg.z + bv.z);
    h4.w = (f16)((v[t].w-mean)*inv*gg.w + bv.w);
    *(f16x4*)(out + row*D_DIM + c0) = h4;
  }
}

// ---------- wave-per-row double LN: out1=LN(X[+X2],g1,b1) f32, out2=LN(out1,g2,b2) f16 ----------
template<bool ADD>
__global__ __launch_bounds__(256) void lnlnw_k(
    const float* __restrict__ X, const float* __restrict__ X2,
    const float* __restrict__ g1, const float* __restrict__ b1,
    const float* __restrict__ g2, const float* __restrict__ b2,
    float* __restrict__ out1, f16* __restrict__ out2)
{
  const int lane = threadIdx.x & 63;
  const size_t row = (size_t)blockIdx.x*4 + (threadIdx.x>>6);
  const float* x = X + row*D_DIM;
  const float* x2 = X2 + row*D_DIM;
  float4 v[3]; float s=0.f, ss=0.f;
  #pragma unroll
  for (int t=0;t<3;++t){
    int c0 = lane*4 + t*256;
    float4 a = *(const float4*)(x + c0);
    if (ADD){
      float4 b = *(const float4*)(x2 + c0);
      a.x+=b.x; a.y+=b.y; a.z+=b.z; a.w+=b.w;
    }
    v[t]=a;
    s  += v[t].x+v[t].y+v[t].z+v[t].w;
    ss += v[t].x*v[t].x+v[t].y*v[t].y+v[t].z*v[t].z+v[t].w*v[t].w;
  }
  #pragma unroll
  for (int m=1;m<64;m<<=1){ s += __shfl_xor(s,m); ss += __shfl_xor(ss,m); }
  float mean = s*(1.0f/768.0f);
  float inv  = rsqrtf(ss*(1.0f/768.0f) - mean*mean + 1e-5f);
  float y[3][4]; float s2=0.f, ss2=0.f;
  #pragma unroll
  for (int t=0;t<3;++t){
    int c0 = lane*4 + t*256;
    float4 gg = *(const float4*)(g1 + c0);
    float4 bv = *(const float4*)(b1 + c0);
    y[t][0] = (v[t].x-mean)*inv*gg.x + bv.x;
    y[t][1] = (v[t].y-mean)*inv*gg.y + bv.y;
    y[t][2] = (v[t].z-mean)*inv*gg.z + bv.z;
    y[t][3] = (v[t].w-mean)*inv*gg.w + bv.w;
    float4 o = { y[t][0], y[t][1], y[t][2], y[t][3] };
    *(float4*)(out1 + row*D_DIM + c0) = o;
    s2  += y[t][0]+y[t][1]+y[t][2]+y[t][3];
    ss2 += y[t][0]*y[t][0]+y[t][1]*y[t][1]+y[t][2]*y[t][2]+y[t][3]*y[t][3];
  }
  #pragma unroll
  for (int m=1;m<64;m<<=1){ s2 += __shfl_xor(s2,m); ss2 += __shfl_xor(ss2,m); }
  float mean2 = s2*(1.0f/768.0f);
  float inv2  = rsqrtf(ss2*(1.0f/768.0f) - mean2*mean2 + 1e-5f);
  #pragma unroll
  for (int t=0;t<3;++t){
    int c0 = lane*4 + t*256;
    float4 gg = *(const float4*)(g2 + c0);
    float4 bv = *(const float4*)(b2 + c0);
    f16x4 h4;
    h4.x = (f16)((y[t][0]-mean2)*inv2*gg.x + bv.x);
    h4.y = (f16)((y[t][1]-mean2)*inv2*gg.y + bv.y);
    h4.z = (f16)((y[t][2]-mean2)*inv2*gg.z + bv.z);
    h4.w = (f16)((y[t][3]-mean2)*inv2*gg.w + bv.w);
    *(f16x4*)(out2 + row*D_DIM + c0) = h4;
  }
}

// ---------- slots init + LN(ns) fused ----------
__global__ __launch_bounds__(256) void slotsinit_k(
    const float* __restrict__ noise, const float* __restrict__ mu,
    const float* __restrict__ ls,
    const float* __restrict__ nsg, const float* __restrict__ nsb,
    float* __restrict__ slots, f16* __restrict__ tmp2)
{
  const int lane = threadIdx.x & 63;
  const size_t row = (size_t)blockIdx.x*4 + (threadIdx.x>>6);
  float4 v[3]; float s=0.f, ss=0.f;
  #pragma unroll
  for (int t=0;t<3;++t){
    int c0 = lane*4 + t*256;
    float4 nz = *(const float4*)(noise + row*D_DIM + c0);
    float4 m4 = *(const float4*)(mu + c0);
    float4 l4 = *(const float4*)(ls + c0);
    v[t].x = m4.x + __expf(l4.x)*nz.x;
    v[t].y = m4.y + __expf(l4.y)*nz.y;
    v[t].z = m4.z + __expf(l4.z)*nz.z;
    v[t].w = m4.w + __expf(l4.w)*nz.w;
    *(float4*)(slots + row*D_DIM + c0) = v[t];
    s  += v[t].x+v[t].y+v[t].z+v[t].w;
    ss += v[t].x*v[t].x+v[t].y*v[t].y+v[t].z*v[t].z+v[t].w*v[t].w;
  }
  #pragma unroll
  for (int m=1;m<64;m<<=1){ s += __shfl_xor(s,m); ss += __shfl_xor(ss,m); }
  float mean = s*(1.0f/768.0f);
  float inv  = rsqrtf(ss*(1.0f/768.0f) - mean*mean + 1e-5f);
  #pragma unroll
  for (int t=0;t<3;++t){
    int c0 = lane*4 + t*256;
    float4 gg = *(const float4*)(nsg + c0);
    float4 bv = *(const float4*)(nsb + c0);
    f16x4 h4;
    h4.x = (f16)((v[t].x-mean)*inv*gg.x + bv.x);
    h4.y = (f16)((v[t].y-mean)*inv*gg.y + bv.y);
    h4.z = (f16)((v[t].z-mean)*inv*gg.z + bv.z);
    h4.w = (f16)((v[t].w-mean)*inv*gg.w + bv.w);
    *(f16x4*)(tmp2 + row*D_DIM + c0) = h4;
  }
}

// ---------- encoder self-attention ----------
__global__ __launch_bounds__(256) void encattn_k(
    const f16* __restrict__ QA, const f16* __restrict__ KA,
    const f16* __restrict__ VA, int QSTR,
    f16* __restrict__ O)
{
  __shared__ float qs[16][68], ks[16][68], vs[16][68], ps[16][20];
  const int b = blockIdx.x, h = blockIdx.y;
  const int tid = threadIdx.x;
  {
    int i = tid>>4, dd=(tid&15)*4;
    size_t base = ((size_t)(b*NSLOT+i))*QSTR + h*64 + dd;
    f16x4 uq = *(const f16x4*)(QA + base);
    f16x4 uk = *(const f16x4*)(KA + base);
    f16x4 uv = *(const f16x4*)(VA + base);
    float4 fq = { (float)uq.x, (float)uq.y, (float)uq.z, (float)uq.w };
    float4 fk = { (float)uk.x, (float)uk.y, (float)uk.z, (float)uk.w };
    float4 fv = { (float)uv.x, (float)uv.y, (float)uv.z, (float)uv.w };
    *(float4*)&qs[i][dd]=fq; *(float4*)&ks[i][dd]=fk; *(float4*)&vs[i][dd]=fv;
  }
  __syncthreads();
  {
    int i = tid>>4, j = tid&15;
    float s=0.f;
    #pragma unroll 8
    for (int d=0; d<64; ++d) s += qs[i][d]*ks[j][d];
    ps[i][j] = s*SCALE_H;
  }
  __syncthreads();
  if (tid < 16){
    int i = tid;
    float mx=-1e30f;
    #pragma unroll
    for (int j=0;j<16;++j) mx = fmaxf(mx, ps[i][j]);
    float sm=0.f;
    #pragma unroll
    for (int j=0;j<16;++j){ float e=__expf(ps[i][j]-mx); ps[i][j]=e; sm+=e; }
    float inv=1.0f/sm;
    #pragma unroll
    for (int j=0;j<16;++j) ps[i][j]*=inv;
  }
  __syncthreads();
  {
    int i = tid>>4, dq=(tid&15)*4;
    float a0=0,a1=0,a2=0,a3=0;
    #pragma unroll
    for (int j=0;j<16;++j){
      float p = ps[i][j];
      a0+=p*vs[j][dq+0]; a1+=p*vs[j][dq+1]; a2+=p*vs[j][dq+2]; a3+=p*vs[j][dq+3];
    }
    size_t base = ((size_t)(b*NSLOT+i))*HDIM + h*64 + dq;
    O[base+0]=(f16)a0; O[base+1]=(f16)a1; O[base+2]=(f16)a2; O[base+3]=(f16)a3;
  }
}

// ---------- f16 transpose: out[C][R] = in[R][C] ----------
__global__ __launch_bounds__(256) void transp_k(
    const f16* __restrict__ in, f16* __restrict__ out, int R, int C)
{
  __shared__ f16 T[64][72];
  const int m0 = blockIdx.x*64, d0 = blockIdx.y*64;
  const int tid = threadIdx.x;
  {
    int r = tid>>2, c = (tid&3)*16;
    const f16* p = in + (size_t)(m0+r)*C + d0 + c;
    *(f16x8*)&T[r][c]   = *(const f16x8*)p;
    *(f16x8*)&T[r][c+8] = *(const f16x8*)(p+8);
  }
  __syncthreads();
  {
    int dd = tid>>2, mq = (tid&3)*16;
    f16 v[16];
    #pragma unroll
    for (int e=0;e<16;++e) v[e] = T[mq+e][dd];
    f16* p = out + (size_t)(d0+dd)*R + m0 + mq;
    *(f16x8*)p     = *(f16x8*)&v[0];
    *(f16x8*)(p+8) = *(f16x8*)&v[8];
  }
}

// ---------- all weight casts/transposes in ONE kernel ----------
__global__ __launch_bounds__(256) void prep_k(
    const float* __restrict__ Wv,   const float* __restrict__ Wq_a,
    const float* __restrict__ Wk_a, const float* __restrict__ Wv_a,
    const float* __restrict__ Wo_a, const float* __restrict__ W1,
    const float* __restrict__ W2,   const float* __restrict__ Wk,
    const float* __restrict__ Wq,
    f16* __restrict__ WvT, f16* __restrict__ WqkvT, f16* __restrict__ WoaT,
    f16* __restrict__ W1T, f16* __restrict__ W2T,
    f16* __restrict__ Wkf, f16* __restrict__ Wqf)
{
  __shared__ float t[32][33];
  int bid = blockIdx.x;
  const float* src; f16* dst; int R, C; bool tr = true;
  if      (bid < 576)  {              src=Wv;   dst=WvT;             R=768;  C=768; }
  else if (bid < 960)  { bid-=576;    src=Wq_a; dst=WqkvT;           R=768;  C=512; }
  else if (bid < 1344) { bid-=960;    src=Wk_a; dst=WqkvT+512*768;   R=768;  C=512; }
  else if (bid < 1728) { bid-=1344;   src=Wv_a; dst=WqkvT+1024*768;  R=768;  C=512; }
  else if (bid < 2112) { bid-=1728;   src=Wo_a; dst=WoaT;            R=512;  C=768; }
  else if (bid < 6720) { bid-=2112;   src=W1;   dst=W1T;             R=768;  C=6144; }
  else if (bid < 9024) { bid-=6720;   src=W2;   dst=W2T;             R=3072; C=768; }
  else if (bid < 9600) { bid-=9024;   src=Wk;   dst=Wkf;             R=768;  C=768; tr=false; }
  else                 { bid-=9600;   src=Wq;   dst=Wqf;             R=768;  C=768; tr=false; }
  const int tpr = C/32;
  const int r0 = (bid / tpr)*32, c0 = (bid % tpr)*32;
  const int lc = threadIdx.x & 31, g8 = threadIdx.x >> 5;
  if (tr){
    #pragma unroll
    for (int s=0;s<4;++s){
      int r = g8*4 + s;
      t[r][lc] = src[(size_t)(r0+r)*C + c0+lc];
    }
    __syncthreads();
    #pragma unroll
    for (int s=0;s<4;++s){
      int c = g8*4 + s;
      dst[(size_t)(c0+c)*R + r0+lc] = (f16)t[lc][c];
    }
  } else {
    #pragma unroll
    for (int s=0;s<4;++s){
      int r = g8*4 + s;
      dst[(size_t)(r0+r)*C + c0+lc] = (f16)src[(size_t)(r0+r)*C + c0+lc];
    }
  }
}

// ---------- attn_map output (rowsum inline) ----------
__global__ __launch_bounds__(256) void attnout_k(
    const f16* __restrict__ attn, const float* __restrict__ rsPart,
    float* __restrict__ out)
{
  __shared__ float rsum[16];
  const int bid = blockIdx.x, tid = threadIdx.x;
  const int b = bid >> 6;
  if (tid < 16){
    float s = 0.f;
    #pragma unroll
    for (int jt=0;jt<16;++jt) s += rsPart[(size_t)((b*16+jt)<<4) + tid];
    rsum[tid] = s;
  }
  __syncthreads();
  int idx = bid*256 + tid;
  int i = idx & 15;
  int j = (idx >> 4) & 1023;
  out[idx] = (float)attn[((size_t)(b*NSLOT)+i)*NTOK + j] / rsum[i];
}

extern "C" void kernel_launch(void* const* d_in, const int* in_sizes, int n_in,
                              void* d_out, int out_size, void* d_ws, size_t ws_size,
                              hipStream_t stream) {
  const float* x        = (const float*)d_in[0];
  const float* noise    = (const float*)d_in[1];
  const float* init_mu  = (const float*)d_in[2];
  const float* init_ls  = (const float*)d_in[3];
  const float* Wk       = (const float*)d_in[4];
  const float* Wv       = (const float*)d_in[5];
  const float* Wq       = (const float*)d_in[6];
  const float* ni_g     = (const float*)d_in[7];
  const float* ni_b     = (const float*)d_in[8];
  const float* ns_g     = (const float*)d_in[9];
  const float* ns_b     = (const float*)d_in[10];
  const float* nica_g   = (const float*)d_in[11];
  const float* nica_b   = (const float*)d_in[12];
  const float* ln1_g    = (const float*)d_in[13];
  const float* ln1_b    = (const float*)d_in[14];
  const float* Wq_a     = (const float*)d_in[15];
  const float* Wk_a     = (const float*)d_in[16];
  const float* Wv_a     = (const float*)d_in[17];
  const float* Wo_a     = (const float*)d_in[18];
  const float* ln2_g    = (const float*)d_in[19];
  const float* ln2_b    = (const float*)d_in[20];
  const float* W1       = (const float*)d_in[21];
  const float* W2       = (const float*)d_in[22];
  const float* lnf_g    = (const float*)d_in[23];
  const float* lnf_b    = (const float*)d_in[24];

  char* w = (char*)d_ws;
  size_t off = 0;
  auto alloc = [&](size_t bytes)->char*{
    char* p = w + off; off += (bytes + 255) & ~(size_t)255; return p;
  };
  f16* xn_h  = (f16*)alloc((size_t)NTOT*D_DIM*2);
  f16* xnT_h = (f16*)alloc((size_t)D_DIM*NTOT*2);
  f16* Wkf   = (f16*)alloc((size_t)768*768*2);
  f16* Wqf   = (f16*)alloc((size_t)768*768*2);
  f16* BtQK  = (f16*)alloc((size_t)768*768*2);
  f16* WvT   = (f16*)alloc((size_t)768*768*2);
  f16* WqkvT = (f16*)alloc((size_t)1536*768*2);
  f16* WoaT  = (f16*)alloc((size_t)768*512*2);
  f16* W1T   = (f16*)alloc((size_t)6144*768*2);
  f16* W2T   = (f16*)alloc((size_t)768*3072*2);
  float* slots = (float*)alloc(512*768*4);
  float* hbuf  = (float*)alloc(512*768*4);
  float* upd   = (float*)alloc(512*768*4);
  f16* tmp_h  = (f16*)alloc(512*768*2);
  f16* tmp2_h = (f16*)alloc(512*768*2);
  f16* q_h    = (f16*)alloc(512*768*2);
  f16* t_h    = (f16*)alloc(512*768*2);
  f16* qkv_h  = (f16*)alloc((size_t)512*1536*2);
  f16* o_h    = (f16*)alloc(512*512*2);
  f16* act_h  = (f16*)alloc((size_t)512*3072*2);
  f16* attn_h = (f16*)alloc((size_t)NB*NSLOT*NTOK*2);
  float* rsPart = (float*)alloc((size_t)32*16*16*4);

  // weight prep: all casts/transposes in one launch
  prep_k<<<10176, 256, 0, stream>>>(Wv, Wq_a, Wk_a, Wv_a, Wo_a, W1, W2, Wk, Wq,
                                    WvT, WqkvT, WoaT, W1T, W2T, Wkf, Wqf);

  // BtQK[f][e] = sum_d Wk[f][d] * Wq[e][d]
  mgemm64_k<1><<<dim3(12, 12, 1), 256, 0, stream>>>(Wkf, Wqf, BtQK, 768, 768, 768, 768);

  // xn = LN(x); xnT = xn^T
  lnw_k<<<NTOT/4, 256, 0, stream>>>(x, ni_g, ni_b, xn_h);
  transp_k<<<dim3(NTOT/64, D_DIM/64), 256, 0, stream>>>(xn_h, xnT_h, NTOT, D_DIM);

  // slots = mu + exp(ls)*noise; tmp2 = LN(slots, ns)
  slotsinit_k<<<128, 256, 0, stream>>>(noise, init_mu, init_ls, ns_g, ns_b,
                                       slots, tmp2_h);

  for (int it=0; it<4; ++it){
    // q_eff = LN(slots,ns) @ (Wq Wk^T)
    mgemm64_k<1><<<dim3(8, 12, 1), 256, 0, stream>>>(tmp2_h, BtQK, q_h, 512, 768, 768, 768);
    // dots = q_eff @ xn^T + inverted softmax
    dots_k<<<dim3(NB, 16), 256, 0, stream>>>(q_h, xn_h, attn_h, rsPart);
    // t = (attn @ xn) / rowsum
    attnv_k<<<dim3(NB, 12), 256, 0, stream>>>(attn_h, rsPart, xnT_h, t_h);
    // upd = t @ Wv
    mgemm64_k<0><<<dim3(8, 12, 1), 256, 0, stream>>>(t_h, WvT, upd, 512, 768, 768, 768);
    // hbuf = LN(slots+upd, nica); tmp = LN(hbuf, ln1)
    lnlnw_k<true><<<128, 256, 0, stream>>>(slots, upd, nica_g, nica_b, ln1_g, ln1_b,
                                           hbuf, tmp_h);
    // qkv = a @ [Wq_a|Wk_a|Wv_a]
    mgemm64_k<1><<<dim3(8, 24, 1), 256, 0, stream>>>(tmp_h, WqkvT, qkv_h, 512, 1536, 768, 768);
    encattn_k<<<dim3(NB, 8), 256, 0, stream>>>(qkv_h, qkv_h + 512, qkv_h + 1024, 1536, o_h);
    // hbuf += o @ Wo_a (split-K=2 atomic, single 256-K step each)
    mgemm64_k<2><<<dim3(8, 12, 2), 256, 0, stream>>>(o_h, WoaT, hbuf, 512, 768, 512, 256);
    // f = LN(hbuf, ln2)
    lnw_k<<<128, 256, 0, stream>>>(hbuf, ln2_g, ln2_b, tmp_h);
    // act = glu(f @ W1)
    w1glu_k<<<dim3(8, 48), 256, 0, stream>>>(tmp_h, W1T, act_h, 512);
    // hbuf += act @ W2 (split-K=4 atomic)
    mgemm64_k<2><<<dim3(8, 12, 4), 256, 0, stream>>>(act_h, W2T, hbuf, 512, 768, 3072, 768);
    // slots = LN(hbuf, lnf) [last iter: straight to d_out]; tmp2 = LN(slots, ns)
    float* out1 = (it==3) ? (float*)d_out : slots;
    lnlnw_k<false><<<128, 256, 0, stream>>>(hbuf, nullptr, lnf_g, lnf_b, ns_g, ns_b,
                                            out1, tmp2_h);
  }

  attnout_k<<<NB*NTOK*NSLOT/256, 256, 0, stream>>>(attn_h, rsPart, (float*)d_out + 512*768);
}